// Round 4
// baseline (216.376 us; speedup 1.0000x reference)
//
#include <hip/hip_runtime.h>

#define B 4
#define T 2048
#define D 1024
#define H 16
#define HD 64
#define NKT 32   // key tiles (64 keys each) per batch

typedef __attribute__((ext_vector_type(8))) short bf16x8;
typedef __attribute__((ext_vector_type(4))) float f32x4;
typedef __attribute__((ext_vector_type(16))) float f32x16;

#define MFMA16(a, b, c) __builtin_amdgcn_mfma_f32_16x16x32_bf16(a, b, c, 0, 0, 0)
#define MFMA32(a, b, c) __builtin_amdgcn_mfma_f32_32x32x16_bf16(a, b, c, 0, 0, 0)

static __device__ __forceinline__ unsigned short f2bf(float f) {
    union { float f; unsigned u; } v; v.f = f;
    unsigned r = v.u + 0x7FFFu + ((v.u >> 16) & 1u);  // RNE
    return (unsigned short)(r >> 16);
}

static __device__ __forceinline__ bf16x8 cvt8(const float* p) {
    float4 a = *(const float4*)p;
    float4 b = *(const float4*)(p + 4);
    bf16x8 r;
    r[0] = (short)f2bf(a.x); r[1] = (short)f2bf(a.y);
    r[2] = (short)f2bf(a.z); r[3] = (short)f2bf(a.w);
    r[4] = (short)f2bf(b.x); r[5] = (short)f2bf(b.y);
    r[6] = (short)f2bf(b.z); r[7] = (short)f2bf(b.w);
    return r;
}

static __device__ __forceinline__ unsigned cvtpk(float lo, float hi) {
    unsigned r;
    asm("v_cvt_pk_bf16_f32 %0, %1, %2" : "=v"(r) : "v"(lo), "v"(hi));
    return r;
}

static __device__ __forceinline__ f32x16 zero16() {
    f32x16 z;
#pragma unroll
    for (int i = 0; i < 16; ++i) z[i] = 0.f;
    return z;
}

// cross-half (lane^32) max / sum via permlane32_swap (VALU, no LDS)
static __device__ __forceinline__ float xhalf_max(float x) {
    unsigned u = __float_as_uint(x);
    auto r = __builtin_amdgcn_permlane32_swap(u, u, false, false);
    return fmaxf(__uint_as_float(r[0]), __uint_as_float(r[1]));
}
static __device__ __forceinline__ float xhalf_sum(float x) {
    unsigned u = __float_as_uint(x);
    auto r = __builtin_amdgcn_permlane32_swap(u, u, false, false);
    return __uint_as_float(r[0]) + __uint_as_float(r[1]);
}

typedef __attribute__((address_space(1))) const unsigned char gl_u8;
typedef __attribute__((address_space(3))) unsigned char lds_u8;

// async global->LDS 16B copy; LDS dest = wave-uniform base + lane*16 (HW)
static __device__ __forceinline__ void stage16(const void* g, void* l) {
    __builtin_amdgcn_global_load_lds((gl_u8*)(unsigned long long)g,
                                     (lds_u8*)(unsigned int)(unsigned long long)l,
                                     16, 0, 0);
}

// ---------------- kernel 1: transpose weights to bf16 (LDS-tiled) ----------
// 18 "heads": 0..15 = Wq heads, 16 = Wk, 17 = Wv. src [D][HD] -> dst [HD][D].
__global__ __launch_bounds__(256) void pack_w(const float* __restrict__ Wq,
                                              const float* __restrict__ Wk,
                                              const float* __restrict__ Wv,
                                              unsigned short* __restrict__ Wqt,
                                              unsigned short* __restrict__ Wkt,
                                              unsigned short* __restrict__ Wvt) {
    __shared__ float tile[64][65];
    int hh = blockIdx.x >> 4, db = blockIdx.x & 15;
    const float* src;
    unsigned short* dst;
    if (hh < 16)      { src = Wq + (size_t)hh * D * HD; dst = Wqt + (size_t)hh * HD * D; }
    else if (hh == 16){ src = Wk; dst = Wkt; }
    else              { src = Wv; dst = Wvt; }
    int r = threadIdx.x >> 6, c = threadIdx.x & 63;
    int d0 = db * 64;
#pragma unroll
    for (int i = 0; i < 16; ++i)
        tile[r * 16 + i][c] = src[(size_t)(d0 + r * 16 + i) * HD + c];
    __syncthreads();
#pragma unroll
    for (int j = 0; j < 16; ++j)
        dst[(size_t)(r * 16 + j) * D + d0 + c] = f2bf(tile[c][r * 16 + j]);
}

// ---------------- kernel 2: K/V projections -> fragment-native 8KB tiles ----
// K tile: chunk ck = dt*2+kt2 (1KB each); byte lane*16 of chunk = bf16x8
//   K[key = kt2*32 + (lane&31)][e = dt*16 + (lane>>5)*8 .. +7].
// V tile: chunk cv = ks*2+e2; byte lane*16 = V^T[e = e2*32 + (lane&31)]
//   [key = ks*16 + (lane>>5)*8 .. +7].
// grp 0 additionally emits xbf (fused cvt_x).
__global__ __launch_bounds__(256) void kv_gemm(const float* __restrict__ xf,
                                               const unsigned short* __restrict__ Wkt,
                                               const unsigned short* __restrict__ Wvt,
                                               const float* __restrict__ bk,
                                               const float* __restrict__ bv,
                                               unsigned short* __restrict__ xbf,
                                               unsigned char* __restrict__ Ksw,
                                               unsigned char* __restrict__ Vsw) {
    int grp = blockIdx.x >> 7;          // 0=K, 1=V
    int rtb = blockIdx.x & 127;
    int wave = threadIdx.x >> 6;
    int lane = threadIdx.x & 63;
    int ln = lane & 15, lk = lane >> 4;
    int rt = rtb * 4 + wave;            // 0..511
    int t0 = rt * 16;                   // global row (b*T + t)

    const unsigned short* Wt = grp ? Wvt : Wkt;
    const float* bias = grp ? bv : bk;

    f32x4 acc[4];
#pragma unroll
    for (int e = 0; e < 4; ++e) acc[e] = (f32x4){0.f, 0.f, 0.f, 0.f};

    for (int d0 = 0; d0 < D; d0 += 32) {
        size_t xi = (size_t)(t0 + ln) * D + d0 + lk * 8;
        bf16x8 a = cvt8(xf + xi);
        if (grp == 0) *(bf16x8*)(xbf + xi) = a;   // fused x->bf16 emit
#pragma unroll
        for (int e = 0; e < 4; ++e) {
            bf16x8 w = *(const bf16x8*)(Wt + (size_t)(e * 16 + ln) * D + d0 + lk * 8);
            acc[e] = MFMA16(a, w, acc[e]);
        }
    }

#pragma unroll
    for (int e = 0; e < 4; ++e)
#pragma unroll
        for (int r = 0; r < 4; ++r) {
            int trow = t0 + lk * 4 + r;
            float val = acc[e][r] + bias[e * 16 + ln];
            int bb = trow >> 11, tl = trow & 2047;
            size_t tbase = ((size_t)(bb * NKT + (tl >> 6))) << 13;
            int key = tl & 63;
            if (grp == 0) {
                // dt = e, hi = ln>>3, j = ln&7
                int off = (e * 2 + (key >> 5)) * 1024 +
                          ((ln >> 3) * 32 + (key & 31)) * 16 + (ln & 7) * 2;
                *(unsigned short*)(Ksw + tbase + off) = f2bf(val);
            } else {
                // ks = key>>4, hiv = (key>>3)&1, j = key&7; e2 = e>>1, l31v
                int off = ((key >> 4) * 2 + (e >> 1)) * 1024 +
                          (((key >> 3) & 1) * 32 + (e & 1) * 16 + ln) * 16 +
                          (key & 7) * 2;
                *(unsigned short*)(Vsw + tbase + off) = f2bf(val);
            }
        }
}

// ---------------- kernel 3: fused Q-proj + flash attention ----------------
// Swapped layout (q = lane&31), fragment-native LDS K/V (conflict-free),
// double-buffered gload_lds staging, defer-max, permlane reductions.
__global__ __launch_bounds__(256, 4) void attn(const unsigned short* __restrict__ xbf,
                                               const unsigned short* __restrict__ Wqt,
                                               const float* __restrict__ bq,
                                               const unsigned char* __restrict__ Ksw,
                                               const unsigned char* __restrict__ Vsw,
                                               float* __restrict__ out) {
    // K0 @0, K1 @8192, V0 @16384, V1 @24576; epilogue reuses as 4x8KB
    __shared__ __align__(16) unsigned char smem[32768];

    int blk = ((blockIdx.x & 7) << 7) | (blockIdx.x >> 3);  // XCD-chunked swizzle
    int qt = blk & 15;
    int h  = (blk >> 4) & 15;
    int b  = blk >> 8;
    int wave = threadIdx.x >> 6, lane = threadIdx.x & 63;
    int l31 = lane & 31, hi = lane >> 5;
    int t0 = qt * 128 + wave * 32;

    const unsigned char* Kt = Ksw + (((size_t)b * NKT) << 13);
    const unsigned char* Vt = Vsw + (((size_t)b * NKT) << 13);
    int soff = wave * 1024 + lane * 16;
    int ldsw = wave * 1024;

    auto STAGE = [&](int kt, int lk, int lv) {
        const unsigned char* gK = Kt + ((size_t)kt << 13);
        const unsigned char* gV = Vt + ((size_t)kt << 13);
        stage16(gK + soff,        smem + lk + ldsw);
        stage16(gK + 4096 + soff, smem + lk + 4096 + ldsw);
        stage16(gV + soff,        smem + lv + ldsw);
        stage16(gV + 4096 + soff, smem + lv + 4096 + ldsw);
    };

    STAGE(0, 0, 16384);   // overlaps with Q-proj below

    // ---- Q^T = Wq[h]^T · X^T  (q = l31, e = crow(r,hi)) ----
    f32x16 qacc[2] = {zero16(), zero16()};
    const unsigned short* Wh = Wqt + (size_t)h * HD * D;
    const unsigned short* xrow  = xbf + (size_t)(b * T + t0 + l31) * D + hi * 8;
    const unsigned short* wrow0 = Wh + (size_t)l31 * D + hi * 8;
    const unsigned short* wrow1 = Wh + (size_t)(32 + l31) * D + hi * 8;
    for (int dk = 0; dk < D; dk += 16) {
        bf16x8 xb = *(const bf16x8*)(xrow + dk);
        qacc[0] = MFMA32(*(const bf16x8*)(wrow0 + dk), xb, qacc[0]);
        qacc[1] = MFMA32(*(const bf16x8*)(wrow1 + dk), xb, qacc[1]);
    }

    const float sl2 = 0.125f * 1.44269504f;   // fold scale*log2(e): log2 domain
    float qv[2][16];
#pragma unroll
    for (int e0 = 0; e0 < 2; ++e0)
#pragma unroll
        for (int r = 0; r < 16; ++r) {
            int crow = (r & 3) + 8 * (r >> 2) + 4 * hi;
            qv[e0][r] = (qacc[e0][r] + bq[h * HD + e0 * 32 + crow]) * sl2;
        }

    // repack Q^T -> B-fragments qf[dt]
    bf16x8 qf[4];
#pragma unroll
    for (int dt = 0; dt < 4; ++dt) {
        int s = dt >> 1;
        int b0 = 8 * (dt & 1), b1 = b0 + 4;
        unsigned c0 = cvtpk(qv[s][b0 + 0], qv[s][b0 + 1]);
        unsigned c1 = cvtpk(qv[s][b0 + 2], qv[s][b0 + 3]);
        unsigned c2 = cvtpk(qv[s][b1 + 0], qv[s][b1 + 1]);
        unsigned c3 = cvtpk(qv[s][b1 + 2], qv[s][b1 + 3]);
        auto r02 = __builtin_amdgcn_permlane32_swap(c0, c2, false, false);
        auto r13 = __builtin_amdgcn_permlane32_swap(c1, c3, false, false);
        union { unsigned u[4]; bf16x8 v; } pu;
        pu.u[0] = r02[0]; pu.u[1] = r13[0]; pu.u[2] = r02[1]; pu.u[3] = r13[1];
        qf[dt] = pu.v;
    }

    const unsigned char* fbase = smem + lane * 16;  // single ds address VGPR

    __syncthreads();   // tile 0 staged (implicit vmcnt drain)

    float mrun = -1e30f, lrun = 0.f;
    f32x16 o[2] = {zero16(), zero16()};

    auto TILE = [&](int ck, int cv, int nxt, int nk, int nv) {
        if (nxt < NKT) STAGE(nxt, nk, nv);   // prefetch next tile (async)

        // ---- QK^T from LDS (fragment-native: base + chunk*1KB) ----
        f32x16 sacc[2] = {zero16(), zero16()};
        __builtin_amdgcn_s_setprio(1);
#pragma unroll
        for (int dt = 0; dt < 4; ++dt) {
            bf16x8 kf0 = *(const bf16x8*)(fbase + ck + (dt * 2 + 0) * 1024);
            bf16x8 kf1 = *(const bf16x8*)(fbase + ck + (dt * 2 + 1) * 1024);
            sacc[0] = MFMA32(kf0, qf[dt], sacc[0]);
            sacc[1] = MFMA32(kf1, qf[dt], sacc[1]);
        }
        __builtin_amdgcn_s_setprio(0);

        // hoist V fragment reads: latency hides under softmax
        bf16x8 vfa[8];
#pragma unroll
        for (int c = 0; c < 8; ++c)
            vfa[c] = *(const bf16x8*)(fbase + cv + c * 1024);

        // ---- online softmax, defer-max (log2 domain) ----
        float mx[8];
#pragma unroll
        for (int i = 0; i < 8; ++i)
            mx[i] = fmaxf(fmaxf(sacc[0][i], sacc[0][i + 8]),
                          fmaxf(sacc[1][i], sacc[1][i + 8]));
#pragma unroll
        for (int i = 0; i < 4; ++i) mx[i] = fmaxf(mx[i], mx[i + 4]);
        float pmax = fmaxf(fmaxf(mx[0], mx[1]), fmaxf(mx[2], mx[3]));
        pmax = xhalf_max(pmax);

        if (__any(pmax - mrun > 8.0f)) {     // rescale only when needed (T13)
            float newm = fmaxf(mrun, pmax);
            float corr = exp2f(mrun - newm);
            mrun = newm;
            lrun *= corr;
#pragma unroll
            for (int e0 = 0; e0 < 2; ++e0)
#pragma unroll
                for (int r = 0; r < 16; ++r) o[e0][r] *= corr;
        }

#pragma unroll
        for (int kt2 = 0; kt2 < 2; ++kt2)
#pragma unroll
            for (int r = 0; r < 16; ++r)
                sacc[kt2][r] = exp2f(sacc[kt2][r] - mrun);

        float sm[8];
#pragma unroll
        for (int i = 0; i < 8; ++i)
            sm[i] = (sacc[0][i] + sacc[0][i + 8]) + (sacc[1][i] + sacc[1][i + 8]);
#pragma unroll
        for (int i = 0; i < 4; ++i) sm[i] += sm[i + 4];
        float rsum = (sm[0] + sm[1]) + (sm[2] + sm[3]);
        lrun += xhalf_sum(rsum);

        // ---- PV: per-ks {cvtpk+permlane -> P^T frag, 2 MFMA} ----
        __builtin_amdgcn_s_setprio(1);
#pragma unroll
        for (int ks = 0; ks < 4; ++ks) {
            int s = ks >> 1;
            int b0 = 8 * (ks & 1), b1 = b0 + 4;
            unsigned c0 = cvtpk(sacc[s][b0 + 0], sacc[s][b0 + 1]);
            unsigned c1 = cvtpk(sacc[s][b0 + 2], sacc[s][b0 + 3]);
            unsigned c2 = cvtpk(sacc[s][b1 + 0], sacc[s][b1 + 1]);
            unsigned c3 = cvtpk(sacc[s][b1 + 2], sacc[s][b1 + 3]);
            auto r02 = __builtin_amdgcn_permlane32_swap(c0, c2, false, false);
            auto r13 = __builtin_amdgcn_permlane32_swap(c1, c3, false, false);
            union { unsigned u[4]; bf16x8 v; } pu;
            pu.u[0] = r02[0]; pu.u[1] = r13[0]; pu.u[2] = r02[1]; pu.u[3] = r13[1];
            o[0] = MFMA32(vfa[ks * 2 + 0], pu.v, o[0]);
            o[1] = MFMA32(vfa[ks * 2 + 1], pu.v, o[1]);
        }
        __builtin_amdgcn_s_setprio(0);

        __syncthreads();   // all waves done with cur bufs; next tile staged
    };

    for (int kt = 0; kt < NKT; kt += 2) {
        TILE(0,    16384, kt + 1, 8192, 24576);
        TILE(8192, 24576, kt + 2, 0,    16384);
    }

    // ---- epilogue: O^T/l -> swizzled LDS transpose -> float4 stores ----
    float inv = 1.f / lrun;
    unsigned char* eb = smem + wave * 8192;   // 32 rows x 256B, XOR-swizzled
#pragma unroll
    for (int e0 = 0; e0 < 2; ++e0)
#pragma unroll
        for (int r = 0; r < 16; ++r) {
            int crow = (r & 3) + 8 * (r >> 2) + 4 * hi;
            int col4 = (e0 * 32 + crow) * 4;
            *(float*)(eb + l31 * 256 + (col4 ^ ((l31 & 15) << 4))) = o[e0][r] * inv;
        }
    __syncthreads();

    int rgrp = lane >> 4;
    int c16 = (lane & 15) * 16;
#pragma unroll
    for (int g = 0; g < 8; ++g) {
        int row = g * 4 + rgrp;
        float4 vv = *(const float4*)(eb + row * 256 + (c16 ^ ((row & 15) << 4)));
        *(float4*)(out + (size_t)(b * T + t0 + row) * D + h * HD + (c16 >> 2)) = vv;
    }
}

// ---------------- launcher ----------------
extern "C" void kernel_launch(void* const* d_in, const int* in_sizes, int n_in,
                              void* d_out, int out_size, void* d_ws, size_t ws_size,
                              hipStream_t stream) {
    const float* x  = (const float*)d_in[0];
    const float* Wq = (const float*)d_in[1];
    const float* bq = (const float*)d_in[2];
    const float* Wk = (const float*)d_in[3];
    const float* bk = (const float*)d_in[4];
    const float* Wv = (const float*)d_in[5];
    const float* bv = (const float*)d_in[6];
    float* out = (float*)d_out;

    unsigned char* ws = (unsigned char*)d_ws;
    unsigned short* xbf = (unsigned short*)(ws);                  // 16,777,216
    unsigned short* Wqt = (unsigned short*)(ws + 16777216);       //  2,097,152
    unsigned short* Wkt = (unsigned short*)(ws + 18874368);       //    131,072
    unsigned short* Wvt = (unsigned short*)(ws + 19005440);       //    131,072
    unsigned char*  Ksw = ws + 19136512;                          //  1,048,576
    unsigned char*  Vsw = ws + 20185088;                          //  1,048,576
    // total 21,233,664 bytes

    pack_w<<<288, 256, 0, stream>>>(Wq, Wk, Wv, Wqt, Wkt, Wvt);
    kv_gemm<<<256, 256, 0, stream>>>(x, Wkt, Wvt, bk, bv, xbf, Ksw, Vsw);
    attn<<<1024, 256, 0, stream>>>(xbf, Wqt, bq, Ksw, Vsw, out);
}

// Round 5
// 181.182 us; speedup vs baseline: 1.1942x; 1.1942x over previous
//
#include <hip/hip_runtime.h>

#define B 4
#define T 2048
#define D 1024
#define H 16
#define HD 64
#define NKT 32   // key tiles (64 keys each) per batch

typedef __attribute__((ext_vector_type(8))) short bf16x8;
typedef __attribute__((ext_vector_type(4))) float f32x4;
typedef __attribute__((ext_vector_type(16))) float f32x16;

#define MFMA16(a, b, c) __builtin_amdgcn_mfma_f32_16x16x32_bf16(a, b, c, 0, 0, 0)
#define MFMA32(a, b, c) __builtin_amdgcn_mfma_f32_32x32x16_bf16(a, b, c, 0, 0, 0)

static __device__ __forceinline__ unsigned short f2bf(float f) {
    union { float f; unsigned u; } v; v.f = f;
    unsigned r = v.u + 0x7FFFu + ((v.u >> 16) & 1u);  // RNE
    return (unsigned short)(r >> 16);
}

static __device__ __forceinline__ bf16x8 cvt8(const float* p) {
    float4 a = *(const float4*)p;
    float4 b = *(const float4*)(p + 4);
    bf16x8 r;
    r[0] = (short)f2bf(a.x); r[1] = (short)f2bf(a.y);
    r[2] = (short)f2bf(a.z); r[3] = (short)f2bf(a.w);
    r[4] = (short)f2bf(b.x); r[5] = (short)f2bf(b.y);
    r[6] = (short)f2bf(b.z); r[7] = (short)f2bf(b.w);
    return r;
}

static __device__ __forceinline__ unsigned cvtpk(float lo, float hi) {
    unsigned r;
    asm("v_cvt_pk_bf16_f32 %0, %1, %2" : "=v"(r) : "v"(lo), "v"(hi));
    return r;
}

static __device__ __forceinline__ float fmax3(float a, float b, float c) {
    return fmaxf(fmaxf(a, b), c);   // fuses to v_max3_f32
}

static __device__ __forceinline__ f32x16 zero16() {
    f32x16 z;
#pragma unroll
    for (int i = 0; i < 16; ++i) z[i] = 0.f;
    return z;
}

// cross-half (lane^32) max / sum via permlane32_swap (VALU, no LDS)
static __device__ __forceinline__ float xhalf_max(float x) {
    unsigned u = __float_as_uint(x);
    auto r = __builtin_amdgcn_permlane32_swap(u, u, false, false);
    return fmaxf(__uint_as_float(r[0]), __uint_as_float(r[1]));
}
static __device__ __forceinline__ float xhalf_sum(float x) {
    unsigned u = __float_as_uint(x);
    auto r = __builtin_amdgcn_permlane32_swap(u, u, false, false);
    return __uint_as_float(r[0]) + __uint_as_float(r[1]);
}

typedef __attribute__((address_space(1))) const unsigned char gl_u8;
typedef __attribute__((address_space(3))) unsigned char lds_u8;

// async global->LDS 16B copy; LDS dest = wave-uniform base + lane*16 (HW)
static __device__ __forceinline__ void stage16(const void* g, void* l) {
    __builtin_amdgcn_global_load_lds((gl_u8*)(unsigned long long)g,
                                     (lds_u8*)(unsigned int)(unsigned long long)l,
                                     16, 0, 0);
}

// ---------------- kernel 1: transpose weights to bf16 (LDS-tiled) ----------
__global__ __launch_bounds__(256) void pack_w(const float* __restrict__ Wq,
                                              const float* __restrict__ Wk,
                                              const float* __restrict__ Wv,
                                              unsigned short* __restrict__ Wqt,
                                              unsigned short* __restrict__ Wkt,
                                              unsigned short* __restrict__ Wvt) {
    __shared__ float tile[64][65];
    int hh = blockIdx.x >> 4, db = blockIdx.x & 15;
    const float* src;
    unsigned short* dst;
    if (hh < 16)      { src = Wq + (size_t)hh * D * HD; dst = Wqt + (size_t)hh * HD * D; }
    else if (hh == 16){ src = Wk; dst = Wkt; }
    else              { src = Wv; dst = Wvt; }
    int r = threadIdx.x >> 6, c = threadIdx.x & 63;
    int d0 = db * 64;
#pragma unroll
    for (int i = 0; i < 16; ++i)
        tile[r * 16 + i][c] = src[(size_t)(d0 + r * 16 + i) * HD + c];
    __syncthreads();
#pragma unroll
    for (int j = 0; j < 16; ++j)
        dst[(size_t)(r * 16 + j) * D + d0 + c] = f2bf(tile[c][r * 16 + j]);
}

// ---------------- kernel 2: K/V projections -> fragment-native 8KB tiles ----
// K tile: chunk ck = dt*2+kt2 (1KB each); byte lane*16 of chunk = bf16x8
//   K[key = kt2*32 + (lane&31)][e = dt*16 + (lane>>5)*8 .. +7].
// V tile: chunk cv = ks*2+e2; byte lane*16 = V^T[e = e2*32 + (lane&31)]
//   [key = ks*16 + (lane>>5)*8 .. +7].
// grp 0 additionally emits xbf (fused cvt_x).
__global__ __launch_bounds__(256) void kv_gemm(const float* __restrict__ xf,
                                               const unsigned short* __restrict__ Wkt,
                                               const unsigned short* __restrict__ Wvt,
                                               const float* __restrict__ bk,
                                               const float* __restrict__ bv,
                                               unsigned short* __restrict__ xbf,
                                               unsigned char* __restrict__ Ksw,
                                               unsigned char* __restrict__ Vsw) {
    int grp = blockIdx.x >> 7;          // 0=K, 1=V
    int rtb = blockIdx.x & 127;
    int wave = threadIdx.x >> 6;
    int lane = threadIdx.x & 63;
    int ln = lane & 15, lk = lane >> 4;
    int rt = rtb * 4 + wave;            // 0..511
    int t0 = rt * 16;                   // global row (b*T + t)

    const unsigned short* Wt = grp ? Wvt : Wkt;
    const float* bias = grp ? bv : bk;

    f32x4 acc[4];
#pragma unroll
    for (int e = 0; e < 4; ++e) acc[e] = (f32x4){0.f, 0.f, 0.f, 0.f};

    for (int d0 = 0; d0 < D; d0 += 32) {
        size_t xi = (size_t)(t0 + ln) * D + d0 + lk * 8;
        bf16x8 a = cvt8(xf + xi);
        if (grp == 0) *(bf16x8*)(xbf + xi) = a;   // fused x->bf16 emit
#pragma unroll
        for (int e = 0; e < 4; ++e) {
            bf16x8 w = *(const bf16x8*)(Wt + (size_t)(e * 16 + ln) * D + d0 + lk * 8);
            acc[e] = MFMA16(a, w, acc[e]);
        }
    }

#pragma unroll
    for (int e = 0; e < 4; ++e)
#pragma unroll
        for (int r = 0; r < 4; ++r) {
            int trow = t0 + lk * 4 + r;
            float val = acc[e][r] + bias[e * 16 + ln];
            int bb = trow >> 11, tl = trow & 2047;
            size_t tbase = ((size_t)(bb * NKT + (tl >> 6))) << 13;
            int key = tl & 63;
            if (grp == 0) {
                int off = (e * 2 + (key >> 5)) * 1024 +
                          ((ln >> 3) * 32 + (key & 31)) * 16 + (ln & 7) * 2;
                *(unsigned short*)(Ksw + tbase + off) = f2bf(val);
            } else {
                int off = ((key >> 4) * 2 + (e >> 1)) * 1024 +
                          (((key >> 3) & 1) * 32 + (e & 1) * 16 + ln) * 16 +
                          (key & 7) * 2;
                *(unsigned short*)(Vsw + tbase + off) = f2bf(val);
            }
        }
}

// ---------------- kernel 3: fused Q-proj + flash attention ----------------
// Swapped layout (q = lane&31), fragment-native LDS K/V (conflict-free),
// double-buffered gload_lds staging, defer-max, permlane reductions.
__global__ __launch_bounds__(256, 4) void attn(const unsigned short* __restrict__ xbf,
                                               const unsigned short* __restrict__ Wqt,
                                               const float* __restrict__ bq,
                                               const unsigned char* __restrict__ Ksw,
                                               const unsigned char* __restrict__ Vsw,
                                               float* __restrict__ out) {
    // K0 @0, K1 @8192, V0 @16384, V1 @24576; epilogue reuses as 4x8KB
    __shared__ __align__(16) unsigned char smem[32768];

    int blk = ((blockIdx.x & 7) << 7) | (blockIdx.x >> 3);  // XCD-chunked swizzle
    int qt = blk & 15;
    int h  = (blk >> 4) & 15;
    int b  = blk >> 8;
    int wave = threadIdx.x >> 6, lane = threadIdx.x & 63;
    int l31 = lane & 31, hi = lane >> 5;
    int t0 = qt * 128 + wave * 32;

    const unsigned char* Kt = Ksw + (((size_t)b * NKT) << 13);
    const unsigned char* Vt = Vsw + (((size_t)b * NKT) << 13);
    int soff = wave * 1024 + lane * 16;
    int ldsw = wave * 1024;

    auto STAGE = [&](int kt, int lk, int lv) {
        const unsigned char* gK = Kt + ((size_t)kt << 13);
        const unsigned char* gV = Vt + ((size_t)kt << 13);
        stage16(gK + soff,        smem + lk + ldsw);
        stage16(gK + 4096 + soff, smem + lk + 4096 + ldsw);
        stage16(gV + soff,        smem + lv + ldsw);
        stage16(gV + 4096 + soff, smem + lv + 4096 + ldsw);
    };

    STAGE(0, 0, 16384);   // overlaps with Q-proj below

    // ---- Q^T = Wq[h]^T · X^T  (q = l31, e = crow(r,hi)) ----
    f32x16 qacc[2] = {zero16(), zero16()};
    const unsigned short* Wh = Wqt + (size_t)h * HD * D;
    const unsigned short* xrow  = xbf + (size_t)(b * T + t0 + l31) * D + hi * 8;
    const unsigned short* wrow0 = Wh + (size_t)l31 * D + hi * 8;
    const unsigned short* wrow1 = Wh + (size_t)(32 + l31) * D + hi * 8;
    for (int dk = 0; dk < D; dk += 16) {
        bf16x8 xb = *(const bf16x8*)(xrow + dk);
        qacc[0] = MFMA32(*(const bf16x8*)(wrow0 + dk), xb, qacc[0]);
        qacc[1] = MFMA32(*(const bf16x8*)(wrow1 + dk), xb, qacc[1]);
    }

    const float sl2 = 0.125f * 1.44269504f;   // fold scale*log2(e): log2 domain
    float qv[2][16];
#pragma unroll
    for (int e0 = 0; e0 < 2; ++e0)
#pragma unroll
        for (int r = 0; r < 16; ++r) {
            int crow = (r & 3) + 8 * (r >> 2) + 4 * hi;
            qv[e0][r] = (qacc[e0][r] + bq[h * HD + e0 * 32 + crow]) * sl2;
        }

    // repack Q^T -> B-fragments qf[dt]
    bf16x8 qf[4];
#pragma unroll
    for (int dt = 0; dt < 4; ++dt) {
        int s = dt >> 1;
        int b0 = 8 * (dt & 1), b1 = b0 + 4;
        unsigned c0 = cvtpk(qv[s][b0 + 0], qv[s][b0 + 1]);
        unsigned c1 = cvtpk(qv[s][b0 + 2], qv[s][b0 + 3]);
        unsigned c2 = cvtpk(qv[s][b1 + 0], qv[s][b1 + 1]);
        unsigned c3 = cvtpk(qv[s][b1 + 2], qv[s][b1 + 3]);
        auto r02 = __builtin_amdgcn_permlane32_swap(c0, c2, false, false);
        auto r13 = __builtin_amdgcn_permlane32_swap(c1, c3, false, false);
        union { unsigned u[4]; bf16x8 v; } pu;
        pu.u[0] = r02[0]; pu.u[1] = r13[0]; pu.u[2] = r02[1]; pu.u[3] = r13[1];
        qf[dt] = pu.v;
    }

    const unsigned char* fbase = smem + lane * 16;  // single ds address VGPR

    __syncthreads();   // tile 0 staged (implicit vmcnt drain)

    float mrun = -1e30f, lrun = 0.f;
    f32x16 o[2] = {zero16(), zero16()};

    auto TILE = [&](int ck, int cv, int nxt, int nk, int nv) {
        if (nxt < NKT) STAGE(nxt, nk, nv);   // prefetch next tile (async)

        // ---- QK^T from LDS (fragment-native: base + chunk*1KB) ----
        f32x16 sacc[2] = {zero16(), zero16()};
        __builtin_amdgcn_s_setprio(1);
#pragma unroll
        for (int dt = 0; dt < 4; ++dt) {
            bf16x8 kf0 = *(const bf16x8*)(fbase + ck + (dt * 2 + 0) * 1024);
            bf16x8 kf1 = *(const bf16x8*)(fbase + ck + (dt * 2 + 1) * 1024);
            sacc[0] = MFMA32(kf0, qf[dt], sacc[0]);
            sacc[1] = MFMA32(kf1, qf[dt], sacc[1]);
        }
        __builtin_amdgcn_s_setprio(0);

        // ---- online softmax, defer-max (log2 domain) ----
#define SV(j) (sacc[(j) >> 4][(j) & 15])
        float mt[11];
#pragma unroll
        for (int i = 0; i < 10; ++i)
            mt[i] = fmax3(SV(3 * i), SV(3 * i + 1), SV(3 * i + 2));
        mt[10] = fmaxf(SV(30), SV(31));
        float y0 = fmax3(mt[0], mt[1], mt[2]);
        float y1 = fmax3(mt[3], mt[4], mt[5]);
        float y2 = fmax3(mt[6], mt[7], mt[8]);
        float y3 = fmax3(mt[9], mt[10], y0);
        float pmax = xhalf_max(fmax3(y1, y2, y3));
#undef SV

        if (__any(pmax - mrun > 8.0f)) {     // rescale only when needed (T13)
            float newm = fmaxf(mrun, pmax);
            float corr = __builtin_amdgcn_exp2f(mrun - newm);
            mrun = newm;
            lrun *= corr;
#pragma unroll
            for (int e0 = 0; e0 < 2; ++e0)
#pragma unroll
                for (int r = 0; r < 16; ++r) o[e0][r] *= corr;
        }

#pragma unroll
        for (int kt2 = 0; kt2 < 2; ++kt2)
#pragma unroll
            for (int r = 0; r < 16; ++r)
                sacc[kt2][r] = __builtin_amdgcn_exp2f(sacc[kt2][r] - mrun);

        float sm[8];
#pragma unroll
        for (int i = 0; i < 8; ++i)
            sm[i] = (sacc[0][i] + sacc[0][i + 8]) + (sacc[1][i] + sacc[1][i + 8]);
#pragma unroll
        for (int i = 0; i < 4; ++i) sm[i] += sm[i + 4];
        float rsum = (sm[0] + sm[1]) + (sm[2] + sm[3]);
        lrun += xhalf_sum(rsum);

        // ---- PV: per-ks {V pair JIT from LDS, cvtpk+permlane, 2 MFMA} ----
        __builtin_amdgcn_s_setprio(1);
#pragma unroll
        for (int ks = 0; ks < 4; ++ks) {
            int s = ks >> 1;
            int b0 = 8 * (ks & 1), b1 = b0 + 4;
            bf16x8 vf0 = *(const bf16x8*)(fbase + cv + (ks * 2 + 0) * 1024);
            bf16x8 vf1 = *(const bf16x8*)(fbase + cv + (ks * 2 + 1) * 1024);
            unsigned c0 = cvtpk(sacc[s][b0 + 0], sacc[s][b0 + 1]);
            unsigned c1 = cvtpk(sacc[s][b0 + 2], sacc[s][b0 + 3]);
            unsigned c2 = cvtpk(sacc[s][b1 + 0], sacc[s][b1 + 1]);
            unsigned c3 = cvtpk(sacc[s][b1 + 2], sacc[s][b1 + 3]);
            auto r02 = __builtin_amdgcn_permlane32_swap(c0, c2, false, false);
            auto r13 = __builtin_amdgcn_permlane32_swap(c1, c3, false, false);
            union { unsigned u[4]; bf16x8 v; } pu;
            pu.u[0] = r02[0]; pu.u[1] = r13[0]; pu.u[2] = r02[1]; pu.u[3] = r13[1];
            o[0] = MFMA32(vf0, pu.v, o[0]);
            o[1] = MFMA32(vf1, pu.v, o[1]);
        }
        __builtin_amdgcn_s_setprio(0);

        __syncthreads();   // all waves done with cur bufs; next tile staged
    };

    for (int kt = 0; kt < NKT; kt += 2) {
        TILE(0,    16384, kt + 1, 8192, 24576);
        TILE(8192, 24576, kt + 2, 0,    16384);
    }

    // ---- epilogue: O^T/l -> swizzled LDS transpose -> float4 stores ----
    float inv = 1.f / lrun;
    unsigned char* eb = smem + wave * 8192;   // 32 rows x 256B, XOR-swizzled
#pragma unroll
    for (int e0 = 0; e0 < 2; ++e0)
#pragma unroll
        for (int r = 0; r < 16; ++r) {
            int crow = (r & 3) + 8 * (r >> 2) + 4 * hi;
            int col4 = (e0 * 32 + crow) * 4;
            *(float*)(eb + l31 * 256 + (col4 ^ ((l31 & 15) << 4))) = o[e0][r] * inv;
        }
    __syncthreads();

    int rgrp = lane >> 4;
    int c16 = (lane & 15) * 16;
#pragma unroll
    for (int g = 0; g < 8; ++g) {
        int row = g * 4 + rgrp;
        float4 vv = *(const float4*)(eb + row * 256 + (c16 ^ ((row & 15) << 4)));
        *(float4*)(out + (size_t)(b * T + t0 + row) * D + h * HD + (c16 >> 2)) = vv;
    }
}

// ---------------- launcher ----------------
extern "C" void kernel_launch(void* const* d_in, const int* in_sizes, int n_in,
                              void* d_out, int out_size, void* d_ws, size_t ws_size,
                              hipStream_t stream) {
    const float* x  = (const float*)d_in[0];
    const float* Wq = (const float*)d_in[1];
    const float* bq = (const float*)d_in[2];
    const float* Wk = (const float*)d_in[3];
    const float* bk = (const float*)d_in[4];
    const float* Wv = (const float*)d_in[5];
    const float* bv = (const float*)d_in[6];
    float* out = (float*)d_out;

    unsigned char* ws = (unsigned char*)d_ws;
    unsigned short* xbf = (unsigned short*)(ws);                  // 16,777,216
    unsigned short* Wqt = (unsigned short*)(ws + 16777216);       //  2,097,152
    unsigned short* Wkt = (unsigned short*)(ws + 18874368);       //    131,072
    unsigned short* Wvt = (unsigned short*)(ws + 19005440);       //    131,072
    unsigned char*  Ksw = ws + 19136512;                          //  1,048,576
    unsigned char*  Vsw = ws + 20185088;                          //  1,048,576
    // total 21,233,664 bytes

    pack_w<<<288, 256, 0, stream>>>(Wq, Wk, Wv, Wqt, Wkt, Wvt);
    kv_gemm<<<256, 256, 0, stream>>>(x, Wkt, Wvt, bk, bv, xbf, Ksw, Vsw);
    attn<<<1024, 256, 0, stream>>>(xbf, Wqt, bq, Ksw, Vsw, out);
}